// Round 10
// baseline (37.106 us; speedup 1.0000x reference)
//
#include <hip/hip_runtime.h>

typedef __bf16 bf16x8 __attribute__((ext_vector_type(8)));
typedef float  f32x4  __attribute__((ext_vector_type(4)));

#define NB 1024
#define NN 128
#define NH 64
#define NOUT 128

__device__ __forceinline__ unsigned short f2b(float f) {
    return __builtin_bit_cast(unsigned short, (__bf16)f);
}

// One block per batch, 256 threads = 4 waves, (256,3) -> 3 blocks/CU (12 waves/CU).
// adj lives in REGISTERS: wave owns nodes [wv*32, wv*32+32) as af[4][2] fragments,
// reused by matA of layers 1,2 and the collapsed layer 3 (r5-verified layout).
// LDS (48 KB): hT0 | hT1 (double-buffered h, 64x256B) | S (128x128B, wave-private).
// Barriers: stage, layer1-end, layer2-end, L3-partials, svec = 5 total.
// matA->matB needs only an in-wave lgkmcnt(0): S rows are written and read by
// the same wave (wave-private S), and matB writes go to the OTHER hT buffer.
__global__ __launch_bounds__(256, 3)
void rsgcn_fused(const int* __restrict__ graph, const float* __restrict__ adj,
                 const float* __restrict__ embed, const float* __restrict__ W1,
                 const float* __restrict__ W2, const float* __restrict__ W3,
                 float* __restrict__ out)
{
    __shared__ __align__(16) char smem[49152];
    char* const hT0 = smem;            // 16 KB  (h, layers 0->1 input; L3 input)
    char* const hT1 = smem + 16384;    // 16 KB
    char* const S_s = smem + 32768;    // 16 KB  (wave-private scratch)
    float* const svecp = (float*)S_s;          // [4][64] L3 partials (S dead)
    float* const svec  = (float*)(S_s + 1024); // [64]

    const int b    = blockIdx.x;
    const int t    = threadIdx.x;
    const int lane = t & 63;
    const int wv   = t >> 6;
    const int l15  = lane & 15;
    const int lg   = lane >> 4;

    // ---------------- issue all global loads ----------------------------------
    const int jq = t & 31;            // embed: nodes 4*jq..+3
    const int d0 = (t >> 5) * 8;      // embed: 8 features
    const int4 g4 = *(const int4*)(graph + b * NN + jq * 4);

    const float* adjb = adj + (size_t)b * (NN * NN);
    float4 av[16];
    #pragma unroll
    for (int kk = 0; kk < 4; ++kk)
        #pragma unroll
        for (int nt = 0; nt < 2; ++nt)
            #pragma unroll
            for (int h = 0; h < 2; ++h)
                av[(kk * 2 + nt) * 2 + h] =
                    *(const float4*)(adjb + (wv * 32 + nt * 16 + l15) * NN
                                     + kk * 32 + lg * 8 + h * 4);

    float ea[4][8];
    *(float4*)&ea[0][0] = *(const float4*)(embed + g4.x * NH + d0);
    *(float4*)&ea[0][4] = *(const float4*)(embed + g4.x * NH + d0 + 4);
    *(float4*)&ea[1][0] = *(const float4*)(embed + g4.y * NH + d0);
    *(float4*)&ea[1][4] = *(const float4*)(embed + g4.y * NH + d0 + 4);
    *(float4*)&ea[2][0] = *(const float4*)(embed + g4.z * NH + d0);
    *(float4*)&ea[2][4] = *(const float4*)(embed + g4.z * NH + d0 + 4);
    *(float4*)&ea[3][0] = *(const float4*)(embed + g4.w * NH + d0);
    *(float4*)&ea[3][4] = *(const float4*)(embed + g4.w * NH + d0 + 4);

    // ---------------- adj -> register fragments (r5-verified layout) ----------
    bf16x8 af[4][2];
    #pragma unroll
    for (int kk = 0; kk < 4; ++kk)
        #pragma unroll
        for (int nt = 0; nt < 2; ++nt) {
            float4 v0 = av[(kk * 2 + nt) * 2 + 0];
            float4 v1 = av[(kk * 2 + nt) * 2 + 1];
            bf16x8 a;
            a[0] = (__bf16)v0.x; a[1] = (__bf16)v0.y; a[2] = (__bf16)v0.z; a[3] = (__bf16)v0.w;
            a[4] = (__bf16)v1.x; a[5] = (__bf16)v1.y; a[6] = (__bf16)v1.z; a[7] = (__bf16)v1.w;
            af[kk][nt] = a;
        }

    // ---------------- embed -> hT0 (packed b64, swizzled) ---------------------
    #pragma unroll
    for (int k = 0; k < 8; ++k) {
        int d = d0 + k;
        ushort4 u;
        u.x = f2b(ea[0][k]); u.y = f2b(ea[1][k]);
        u.z = f2b(ea[2][k]); u.w = f2b(ea[3][k]);
        *(ushort4*)(hT0 + d * 256 + ((jq * 8) ^ ((d & 7) << 4))) = u;
    }
    __syncthreads();   // barrier 1: hT0 complete

    // ---------------- layers 1,2 ----------------------------------------------
    const char* hTin  = hT0;
    char*       hTout = hT1;
    #pragma unroll
    for (int layer = 0; layer < 2; ++layer) {
        const float* W = layer ? W2 : W1;

        // W fragments (L2-resident; issued early so latency hides under matA)
        bf16x8 wf[2][4];
        #pragma unroll
        for (int k2 = 0; k2 < 2; ++k2)
            #pragma unroll
            for (int dt = 0; dt < 4; ++dt) {
                const float4* p = (const float4*)(W + (dt * 16 + l15) * NH
                                                  + k2 * 32 + lg * 8);
                float4 v0 = p[0], v1 = p[1];
                bf16x8 a;
                a[0] = (__bf16)v0.x; a[1] = (__bf16)v0.y; a[2] = (__bf16)v0.z; a[3] = (__bf16)v0.w;
                a[4] = (__bf16)v1.x; a[5] = (__bf16)v1.y; a[6] = (__bf16)v1.z; a[7] = (__bf16)v1.w;
                wf[k2][dt] = a;
            }

        // ---- matA: S^T[d][own nodes] = sum_j hT[d][j] * adj[node][j] ---------
        {
            f32x4 acc[4][2] = {};
            #pragma unroll
            for (int kk = 0; kk < 4; ++kk) {
                const int kb = kk * 64 + lg * 16;
                bf16x8 ha[4];
                #pragma unroll
                for (int dt = 0; dt < 4; ++dt) {
                    int r = dt * 16 + l15;
                    ha[dt] = *(const bf16x8*)(hTin + r * 256 + (kb ^ ((r & 7) << 4)));
                }
                #pragma unroll
                for (int nt = 0; nt < 2; ++nt)
                    #pragma unroll
                    for (int dt = 0; dt < 4; ++dt)
                        acc[dt][nt] = __builtin_amdgcn_mfma_f32_16x16x32_bf16(
                            ha[dt], af[kk][nt], acc[dt][nt], 0, 0, 0);
            }
            #pragma unroll
            for (int dt = 0; dt < 4; ++dt)
                #pragma unroll
                for (int nt = 0; nt < 2; ++nt) {
                    int node = wv * 32 + nt * 16 + l15;
                    int dd0  = dt * 16 + lg * 4;
                    ushort4 u;
                    u.x = f2b(acc[dt][nt][0]); u.y = f2b(acc[dt][nt][1]);
                    u.z = f2b(acc[dt][nt][2]); u.w = f2b(acc[dt][nt][3]);
                    *(ushort4*)(S_s + node * 128 + ((dd0 * 2) ^ ((node & 7) << 4))) = u;
                }
        }
        // wave-private S: only an in-wave drain needed (no __syncthreads)
        asm volatile("s_waitcnt lgkmcnt(0)" ::: "memory");

        // ---- matB: h'[own nodes][dout] = relu(sum_d S[node][d] W[dout][d]) ---
        {
            f32x4 acc2[2][4] = {};
            #pragma unroll
            for (int k2 = 0; k2 < 2; ++k2) {
                const int kb = k2 * 64 + lg * 16;
                #pragma unroll
                for (int nt = 0; nt < 2; ++nt) {
                    int row = wv * 32 + nt * 16 + l15;
                    bf16x8 sa = *(const bf16x8*)(S_s + row * 128 + (kb ^ ((row & 7) << 4)));
                    #pragma unroll
                    for (int dt = 0; dt < 4; ++dt)
                        acc2[nt][dt] = __builtin_amdgcn_mfma_f32_16x16x32_bf16(
                            sa, wf[k2][dt], acc2[nt][dt], 0, 0, 0);
                }
            }
            #pragma unroll
            for (int nt = 0; nt < 2; ++nt)
                #pragma unroll
                for (int dt = 0; dt < 4; ++dt) {
                    int dout  = dt * 16 + l15;
                    int node0 = wv * 32 + nt * 16 + lg * 4;
                    ushort4 u;
                    u.x = f2b(fmaxf(acc2[nt][dt][0], 0.f));
                    u.y = f2b(fmaxf(acc2[nt][dt][1], 0.f));
                    u.z = f2b(fmaxf(acc2[nt][dt][2], 0.f));
                    u.w = f2b(fmaxf(acc2[nt][dt][3], 0.f));
                    *(ushort4*)(hTout + dout * 256 + ((node0 * 2) ^ ((dout & 7) << 4))) = u;
                }
        }
        __syncthreads();   // barrier 2/3: publish hTout to all waves

        const char* tmp = hTin; hTin = hTout; hTout = (char*)tmp;
    }

    // ---------------- layer 3: svec[d] = sum_node (adj @ h2)^T[d][node] -------
    // hTin == hT0 here (L1: hT0->hT1, L2: hT1->hT0).
    {
        f32x4 acc3[4][2] = {};
        #pragma unroll
        for (int kk = 0; kk < 4; ++kk) {
            const int kb = kk * 64 + lg * 16;
            bf16x8 ha[4];
            #pragma unroll
            for (int dt = 0; dt < 4; ++dt) {
                int r = dt * 16 + l15;
                ha[dt] = *(const bf16x8*)(hTin + r * 256 + (kb ^ ((r & 7) << 4)));
            }
            #pragma unroll
            for (int nt = 0; nt < 2; ++nt)
                #pragma unroll
                for (int dt = 0; dt < 4; ++dt)
                    acc3[dt][nt] = __builtin_amdgcn_mfma_f32_16x16x32_bf16(
                        ha[dt], af[kk][nt], acc3[dt][nt], 0, 0, 0);
        }
        f32x4 s[4];
        #pragma unroll
        for (int dt = 0; dt < 4; ++dt) s[dt] = acc3[dt][0] + acc3[dt][1];
        #pragma unroll
        for (int m = 1; m <= 8; m <<= 1)
            #pragma unroll
            for (int dt = 0; dt < 4; ++dt)
                #pragma unroll
                for (int i = 0; i < 4; ++i)
                    s[dt][i] += __shfl_xor(s[dt][i], m);
        if (l15 == 0) {
            #pragma unroll
            for (int dt = 0; dt < 4; ++dt)
                *(f32x4*)(svecp + wv * 64 + dt * 16 + lg * 4) = s[dt];
        }
    }
    __syncthreads();   // barrier 4

    if (t < 64)
        svec[t] = (svecp[t] + svecp[64 + t]) + (svecp[128 + t] + svecp[192 + t]);
    __syncthreads();   // barrier 5

    // ---------------- out[b][o] = sum_d W3[o][d] * svec[d] (fp32) -------------
    if (t < 128) {
        const float4* wrow = (const float4*)(W3 + t * NH);
        float a0 = 0.f, a1 = 0.f;
        #pragma unroll
        for (int q = 0; q < 16; q += 2) {
            float4 w0 = wrow[q], w1 = wrow[q + 1];
            a0 += w0.x*svec[q*4+0] + w0.y*svec[q*4+1] + w0.z*svec[q*4+2] + w0.w*svec[q*4+3];
            a1 += w1.x*svec[q*4+4] + w1.y*svec[q*4+5] + w1.z*svec[q*4+6] + w1.w*svec[q*4+7];
        }
        out[b * NOUT + t] = a0 + a1;
    }
}

extern "C" void kernel_launch(void* const* d_in, const int* in_sizes, int n_in,
                              void* d_out, int out_size, void* d_ws, size_t ws_size,
                              hipStream_t stream) {
    const int*   graph = (const int*)d_in[0];
    const float* adjp  = (const float*)d_in[1];
    const float* embed = (const float*)d_in[2];
    const float* W1    = (const float*)d_in[3];
    const float* W2    = (const float*)d_in[4];
    const float* W3    = (const float*)d_in[5];
    float* outp = (float*)d_out;

    rsgcn_fused<<<dim3(NB), dim3(256), 0, stream>>>(graph, adjp, embed, W1, W2, W3, outp);
}